// Round 1
// baseline (2286.516 us; speedup 1.0000x reference)
//
#include <hip/hip_runtime.h>
#include <hip/hip_bf16.h>
#include <math.h>

typedef __attribute__((ext_vector_type(4))) float f32x4;
typedef __attribute__((ext_vector_type(8))) short s16x8;

#define MFMA16(a, b, c) __builtin_amdgcn_mfma_f32_16x16x32_bf16(a, b, c, 0, 0, 0)

static constexpr int BB = 32, TT = 128, EE = 512, HH = 1024, VV = 32000;
static constexpr int FH = 4 * HH;          // 4096 gate rows
static constexpr int MROWS = (TT - 1) * BB; // 4064 valid rows
static constexpr int MPAD = 4096;          // padded to tile multiple

__device__ __forceinline__ unsigned short f2bf(float f) {
  unsigned int u = __float_as_uint(f);
  u = (u + 0x7FFFu + ((u >> 16) & 1u)) >> 16;
  return (unsigned short)u;
}
__device__ __forceinline__ float sigf(float x) { return 1.f / (1.f + __expf(-x)); }

// ---------------- zero / convert / embed ----------------

__global__ void zero_k(uint4* __restrict__ p, int n16) {
  int i = blockIdx.x * blockDim.x + threadIdx.x;
  int stride = gridDim.x * blockDim.x;
  uint4 z = {0u, 0u, 0u, 0u};
  for (; i < n16; i += stride) p[i] = z;
}

__global__ void cvt_bf16(const float* __restrict__ in, unsigned short* __restrict__ out, int n) {
  int i = blockIdx.x * blockDim.x + threadIdx.x;
  int stride = gridDim.x * blockDim.x;
  for (; i < n; i += stride) out[i] = f2bf(in[i]);
}

__global__ __launch_bounds__(256) void embed_k(const int* __restrict__ captions,
                                               const float* __restrict__ etab,
                                               const float* __restrict__ pos,
                                               unsigned short* __restrict__ X) {
  const int m = blockIdx.x;  // 0..4095 : row = t*32 + b
  const int t = m >> 5, b = m & 31;
  if (t < TT - 1) {
    const int tok = captions[b * TT + t];
    const float* er = etab + (size_t)tok * EE;
    for (int e = threadIdx.x; e < EE; e += 256)
      X[(size_t)m * EE + e] = f2bf(er[e] + pos[e]);
  } else {
    for (int e = threadIdx.x; e < EE; e += 256) X[(size_t)m * EE + e] = 0;
  }
}

__global__ void zero_out_t0(float* __restrict__ out) {
  // out[b, 0, :] = 0 ; grid (125, 32), block 256
  out[(size_t)blockIdx.y * TT * VV + blockIdx.x * 256 + threadIdx.x] = 0.f;
}

// ---------------- generic C = A @ B^T bf16 MFMA GEMM (128x128 tile) ----------------
// A: (MPAD x K) bf16 row-major, Bm: (N x K) bf16 row-major.
// mode 0: Cout[m*N + col] = acc + bias0[col] + bias1[col]      (G0pre)
// mode 1: Cout[(b*T + t+1)*V + col] = acc + bias0[col]          (projection)

__global__ __launch_bounds__(256) void gemm_bt(const unsigned short* __restrict__ A,
                                               const unsigned short* __restrict__ Bm,
                                               int K, int N, int mode,
                                               const float* __restrict__ bias0,
                                               const float* __restrict__ bias1,
                                               float* __restrict__ Cout) {
  __shared__ unsigned short As[128 * 72];
  __shared__ unsigned short Bs[128 * 72];
  const int tid = threadIdx.x;
  const int lane = tid & 63, wave = tid >> 6;
  const int wm = wave & 1, wn = wave >> 1;
  const int m0 = blockIdx.x * 128, n0 = blockIdx.y * 128;
  f32x4 acc[4][4] = {};

  for (int k0 = 0; k0 < K; k0 += 64) {
    __syncthreads();
#pragma unroll
    for (int i = 0; i < 4; ++i) {
      int idx = tid + i * 256;
      int r = idx >> 3, ch = idx & 7;
      *(uint4*)(&As[r * 72 + ch * 8]) = *(const uint4*)(&A[(size_t)(m0 + r) * K + k0 + ch * 8]);
      *(uint4*)(&Bs[r * 72 + ch * 8]) = *(const uint4*)(&Bm[(size_t)(n0 + r) * K + k0 + ch * 8]);
    }
    __syncthreads();
#pragma unroll
    for (int kk = 0; kk < 64; kk += 32) {
      s16x8 af[4], bf[4];
#pragma unroll
      for (int f = 0; f < 4; ++f) {
        af[f] = *(const s16x8*)(&As[(wm * 64 + f * 16 + (lane & 15)) * 72 + kk + (lane >> 4) * 8]);
        bf[f] = *(const s16x8*)(&Bs[(wn * 64 + f * 16 + (lane & 15)) * 72 + kk + (lane >> 4) * 8]);
      }
#pragma unroll
      for (int mi = 0; mi < 4; ++mi)
#pragma unroll
        for (int ni = 0; ni < 4; ++ni)
          acc[mi][ni] = MFMA16(af[mi], bf[ni], acc[mi][ni]);
    }
  }

#pragma unroll
  for (int mi = 0; mi < 4; ++mi) {
#pragma unroll
    for (int ni = 0; ni < 4; ++ni) {
      const int col = n0 + wn * 64 + ni * 16 + (lane & 15);
      float bs = bias0[col] + (bias1 ? bias1[col] : 0.f);
      const int mbase = m0 + wm * 64 + mi * 16 + (lane >> 4) * 4;
#pragma unroll
      for (int r = 0; r < 4; ++r) {
        int m = mbase + r;
        if (m < MROWS) {
          float v = acc[mi][ni][r] + bs;
          if (mode == 0) {
            Cout[(size_t)m * N + col] = v;
          } else {
            int t = m >> 5, b = m & 31;
            Cout[((size_t)b * TT + (t + 1)) * VV + col] = v;
          }
        }
      }
    }
  }
}

// ---------------- fused LSTM phase kernel ----------------
// blocks 0..255  : layer0 step t      (if do_l0)  gates = G0pre[t] + h0_prev @ Whh0^T
// blocks 256..511: layer1 step t-1    (if do_l1)  gates = h0 @ Wih1^T + h1_prev @ Whh1^T + b1
// Each block owns 4 h-indices; the 16 MFMA B-fragment columns are the 4 gates x 4 h rows of W.

__global__ __launch_bounds__(256) void lstm_pair(const unsigned short* __restrict__ h0read,
                                                 unsigned short* __restrict__ h0write,
                                                 const unsigned short* __restrict__ Whh0,
                                                 const unsigned short* __restrict__ Wih1,
                                                 const unsigned short* __restrict__ Whh1,
                                                 const float* __restrict__ G0pre,
                                                 const float* __restrict__ bih1,
                                                 const float* __restrict__ bhh1,
                                                 float* __restrict__ c0,
                                                 float* __restrict__ c1,
                                                 unsigned short* __restrict__ hs_all,
                                                 int t, int do_l0, int do_l1) {
  __shared__ float parts[4][2][16][16];
  const int layer = (blockIdx.x >= 256) ? 1 : 0;
  if (layer == 0 && !do_l0) return;
  if (layer == 1 && !do_l1) return;
  const int blk = blockIdx.x & 255;
  const int tid = threadIdx.x, lane = tid & 63, wave = tid >> 6;
  const int jb = blk * 4;
  const int colIdx = lane & 15;
  const int col = (colIdx >> 2) * HH + jb + (colIdx & 3);  // gate row in W

  f32x4 acc0 = {}, acc1 = {};

  if (layer == 0) {
    const unsigned short* Wr = Whh0 + (size_t)col * HH;
    const unsigned short* a0p = h0read + (lane & 15) * HH;
    const unsigned short* a1p = h0read + (16 + (lane & 15)) * HH;
    const int kb = wave * 256 + (lane >> 4) * 8;  // K=1024 split over 4 waves
#pragma unroll
    for (int ks = 0; ks < 8; ++ks) {
      int k = kb + ks * 32;
      s16x8 bv = *(const s16x8*)(Wr + k);
      acc0 = MFMA16(*(const s16x8*)(a0p + k), bv, acc0);
      acc1 = MFMA16(*(const s16x8*)(a1p + k), bv, acc1);
    }
  } else {
    const int ttm = t - 1;
    const unsigned short* h1prev = hs_all + (size_t)ttm * (BB * HH);
    const unsigned short* Arow = (wave < 2) ? h0read : h1prev;
    const unsigned short* Wb = (wave < 2) ? Wih1 : Whh1;
    const unsigned short* Wr = Wb + (size_t)col * HH;
    const unsigned short* a0p = Arow + (lane & 15) * HH;
    const unsigned short* a1p = Arow + (16 + (lane & 15)) * HH;
    const int kb = (wave & 1) * 512 + (lane >> 4) * 8;  // each half-K split over 2 waves
#pragma unroll
    for (int ks = 0; ks < 16; ++ks) {
      int k = kb + ks * 32;
      s16x8 bv = *(const s16x8*)(Wr + k);
      acc0 = MFMA16(*(const s16x8*)(a0p + k), bv, acc0);
      acc1 = MFMA16(*(const s16x8*)(a1p + k), bv, acc1);
    }
  }

#pragma unroll
  for (int r = 0; r < 4; ++r) {
    parts[wave][0][(lane >> 4) * 4 + r][colIdx] = acc0[r];
    parts[wave][1][(lane >> 4) * 4 + r][colIdx] = acc1[r];
  }
  __syncthreads();

  if (tid < 128) {
    const int b = tid & 31, jj = tid >> 5;  // jj 0..3
    float g[4];
#pragma unroll
    for (int gi = 0; gi < 4; ++gi) {
      const int c = gi * 4 + jj;
      float s;
      if (layer == 0)
        s = G0pre[(size_t)(t * BB + b) * FH + gi * HH + jb + jj];
      else
        s = bih1[gi * HH + jb + jj] + bhh1[gi * HH + jb + jj];
#pragma unroll
      for (int w = 0; w < 4; ++w) s += parts[w][b >> 4][b & 15][c];
      g[gi] = s;
    }
    const float gi_ = sigf(g[0]), gf_ = sigf(g[1]), gg_ = tanhf(g[2]), go_ = sigf(g[3]);
    const int hidx = b * HH + jb + jj;
    float* cbuf = (layer == 0) ? c0 : c1;
    const float cn = gf_ * cbuf[hidx] + gi_ * gg_;
    cbuf[hidx] = cn;
    const float hv = go_ * tanhf(cn);
    if (layer == 0)
      h0write[hidx] = f2bf(hv);
    else
      hs_all[(size_t)t * (BB * HH) + hidx] = f2bf(hv);  // slot (t-1)+1 = t
  }
}

// ---------------- host ----------------

extern "C" void kernel_launch(void* const* d_in, const int* in_sizes, int n_in,
                              void* d_out, int out_size, void* d_ws, size_t ws_size,
                              hipStream_t stream) {
  const int* captions = (const int*)d_in[1];
  const float* etab = (const float*)d_in[2];
  const float* pos = (const float*)d_in[3];
  const float* Wih0 = (const float*)d_in[4];
  const float* Whh0 = (const float*)d_in[5];
  const float* bih0 = (const float*)d_in[6];
  const float* bhh0 = (const float*)d_in[7];
  const float* Wih1 = (const float*)d_in[8];
  const float* Whh1 = (const float*)d_in[9];
  const float* bih1 = (const float*)d_in[10];
  const float* bhh1 = (const float*)d_in[11];
  const float* Wout = (const float*)d_in[12];
  const float* bout = (const float*)d_in[13];
  float* out = (float*)d_out;

  char* w = (char*)d_ws;
  auto alloc = [&](size_t bytes) {
    char* p = w;
    w += (bytes + 255) & ~(size_t)255;
    return p;
  };
  // zeroed region (contiguous): hs_all + c0 + c1 + h0 ping-pong
  unsigned short* hs_all = (unsigned short*)alloc((size_t)4160 * HH * 2);  // slot0 = h1(-1)=0, slots 1..127, pad
  float* c0 = (float*)alloc((size_t)BB * HH * 4);
  float* c1 = (float*)alloc((size_t)BB * HH * 4);
  unsigned short* h0buf = (unsigned short*)alloc((size_t)2 * BB * HH * 2);
  const size_t zero_bytes = (size_t)(w - (char*)d_ws);

  unsigned short* Xb = (unsigned short*)alloc((size_t)MPAD * EE * 2);
  unsigned short* Wih0b = (unsigned short*)alloc((size_t)FH * EE * 2);
  unsigned short* Whh0b = (unsigned short*)alloc((size_t)FH * HH * 2);
  unsigned short* Wih1b = (unsigned short*)alloc((size_t)FH * HH * 2);
  unsigned short* Whh1b = (unsigned short*)alloc((size_t)FH * HH * 2);
  unsigned short* Woutb = (unsigned short*)alloc((size_t)VV * HH * 2);
  float* G0pre = (float*)alloc((size_t)MROWS * FH * 4);

  // 1) zero state buffers
  hipLaunchKernelGGL(zero_k, dim3(2048), dim3(256), 0, stream, (uint4*)d_ws,
                     (int)(zero_bytes / 16));
  // 2) convert weights to bf16
  hipLaunchKernelGGL(cvt_bf16, dim3(1024), dim3(256), 0, stream, Wih0, Wih0b, FH * EE);
  hipLaunchKernelGGL(cvt_bf16, dim3(1024), dim3(256), 0, stream, Whh0, Whh0b, FH * HH);
  hipLaunchKernelGGL(cvt_bf16, dim3(1024), dim3(256), 0, stream, Wih1, Wih1b, FH * HH);
  hipLaunchKernelGGL(cvt_bf16, dim3(1024), dim3(256), 0, stream, Whh1, Whh1b, FH * HH);
  hipLaunchKernelGGL(cvt_bf16, dim3(2048), dim3(256), 0, stream, Wout, Woutb, VV * HH);
  // 3) embeddings + pos -> X (bf16, padded rows zeroed)
  hipLaunchKernelGGL(embed_k, dim3(MPAD), dim3(256), 0, stream, captions, etab, pos, Xb);
  // 4) G0pre = X @ Wih0^T + bih0 + bhh0
  hipLaunchKernelGGL(gemm_bt, dim3(32, 32), dim3(256), 0, stream, Xb, Wih0b, EE, FH, 0, bih0,
                     bhh0, G0pre);
  // 5) recurrence: phase t does layer0(t) and layer1(t-1)
  for (int t = 0; t < TT; ++t) {
    hipLaunchKernelGGL(lstm_pair, dim3(512), dim3(256), 0, stream,
                       h0buf + (size_t)(t & 1) * BB * HH,
                       h0buf + (size_t)((t + 1) & 1) * BB * HH, Whh0b, Wih1b, Whh1b, G0pre,
                       bih1, bhh1, c0, c1, hs_all, t, (int)(t < TT - 1), (int)(t >= 1));
  }
  // 6) projection: logits = hs @ Wout^T + bout   (A = hs_all skipping slot 0)
  hipLaunchKernelGGL(gemm_bt, dim3(32, 250), dim3(256), 0, stream, hs_all + (size_t)BB * HH,
                     Woutb, HH, VV, 1, bout, nullptr, out);
  // 7) out[:, 0, :] = 0
  hipLaunchKernelGGL(zero_out_t0, dim3(125, 32), dim3(256), 0, stream, out);
}